// Round 5
// baseline (251.716 us; speedup 1.0000x reference)
//
#include <hip/hip_runtime.h>
#include <hip/hip_bf16.h>

// Problem constants (from reference)
#define BB 4
#define CC 64
#define NXX 432
#define NYY 496
#define GG (NXX * NYY)          // 214272 cells per batch
#define PP 80000                // total pillars (B * P_PER)

typedef float v4f __attribute__((ext_vector_type(4)));

// Reference reduces to a dense BEV scatter: prob_buf is zeros (kept bug) so
// p == 0 -> out = spatial. Output [B,C,NY,NX] = pillar_features scattered.
//
// Two kernels only:
//  1) scatter pillar ids into a cell->pillar map in d_ws (NO init pass --
//     the gather validates entries against coords, so any ws garbage is safe)
//  2) gather: thread = 4 consecutive cells x 16 channels; occupied cells
//     verified via coords round-trip; loads predicated (9.3% occupancy);
//     nontemporal float4 stores.

__global__ void k_scatter_ids(const int* __restrict__ coords, int* __restrict__ map) {
    int i = blockIdx.x * blockDim.x + threadIdx.x;
    if (i < PP) {
        int4 cd = ((const int4*)coords)[i];          // (b, z, y, x), z == 0
        int g = cd.x * GG + cd.y + cd.z * NXX + cd.w;
        map[g] = i;
    }
}

__global__ void __launch_bounds__(256) k_gather(const float* __restrict__ pf,
                                                const int* __restrict__ map,
                                                const int4* __restrict__ coords,
                                                float* __restrict__ out) {
    int t = blockIdx.x * blockDim.x + threadIdx.x;   // cell-quad id
    const int nGroups = (BB * GG) / 4;               // 214272 = 837*256 exactly
    if (t >= nGroups) return;

    int cellBase = t * 4;                            // global cell id of cell 0
    int b = cellBase / GG;                           // G%4==0: quad never crosses batch
    int cellInB = cellBase - b * GG;

    int4 pids = ((const int4*)map)[t];
    int p[4] = {pids.x, pids.y, pids.z, pids.w};

    // Validate: in range AND coords[pid] maps back to this exact cell.
    // Robust against ANY d_ws garbage (0xAA poison, zeros, stale data).
    bool v[4];
    #pragma unroll
    for (int k = 0; k < 4; ++k) {
        v[k] = ((unsigned)p[k] < (unsigned)PP);
        if (v[k]) {
            int4 cd = coords[p[k]];
            v[k] = (cd.x * GG + cd.y + cd.z * NXX + cd.w) == (cellBase + k);
        }
    }

    const v4f* pf4 = (const v4f*)pf;                 // pf rows: 64 floats = 16 vec4
    int qBase = blockIdx.y * 4;                      // this slice: q = qBase..qBase+3

    // Predicated loads: only occupied cells (9.3%) touch pf.
    v4f rc[4][4];                                    // [cell][j]
    #pragma unroll
    for (int k = 0; k < 4; ++k) {
        #pragma unroll
        for (int j = 0; j < 4; ++j) rc[k][j] = (v4f)(0.f);
        if (v[k]) {
            int base = p[k] * 16 + qBase;
            #pragma unroll
            for (int j = 0; j < 4; ++j) rc[k][j] = pf4[base + j];
        }
    }

    float* outBase = out + (size_t)(b * CC) * GG + cellInB;
    #pragma unroll
    for (int j = 0; j < 4; ++j) {
        int c0 = (qBase + j) * 4;                    // first of 4 channels
        v4f w0 = (v4f){rc[0][j].x, rc[1][j].x, rc[2][j].x, rc[3][j].x};
        v4f w1 = (v4f){rc[0][j].y, rc[1][j].y, rc[2][j].y, rc[3][j].y};
        v4f w2 = (v4f){rc[0][j].z, rc[1][j].z, rc[2][j].z, rc[3][j].z};
        v4f w3 = (v4f){rc[0][j].w, rc[1][j].w, rc[2][j].w, rc[3][j].w};

        __builtin_nontemporal_store(w0, (v4f*)(outBase + (size_t)(c0 + 0) * GG));
        __builtin_nontemporal_store(w1, (v4f*)(outBase + (size_t)(c0 + 1) * GG));
        __builtin_nontemporal_store(w2, (v4f*)(outBase + (size_t)(c0 + 2) * GG));
        __builtin_nontemporal_store(w3, (v4f*)(outBase + (size_t)(c0 + 3) * GG));
    }
}

extern "C" void kernel_launch(void* const* d_in, const int* in_sizes, int n_in,
                              void* d_out, int out_size, void* d_ws, size_t ws_size,
                              hipStream_t stream) {
    const float* pf     = (const float*)d_in[0];     // [80000, 64] f32
    const int*   coords = (const int*)d_in[7];       // [80000, 4] i32 (b,z,y,x)
    float*       out    = (float*)d_out;             // [B, C, NY, NX] f32
    int*         map    = (int*)d_ws;                // [B*G] i32 cell->pillar (3.43 MB)

    k_scatter_ids<<<dim3((PP + 255) / 256), dim3(256), 0, stream>>>(coords, map);

    const int nGroups = (BB * GG) / 4;               // 214272 = 837 * 256 exactly
    dim3 grid((nGroups + 255) / 256, 4);             // 837 x 4 blocks, 16 ch each
    k_gather<<<grid, dim3(256), 0, stream>>>(pf, map, (const int4*)coords, out);
}